// Round 2
// baseline (186.961 us; speedup 1.0000x reference)
//
#include <hip/hip_runtime.h>

#define NB   8192
#define HW   4096   // 64*64

// Main kernel: one 64-lane wave per sample. 4 waves (256 threads) per block,
// grid = NB/4. Each lane processes 64 elements (16 float4 loads, fully
// unrolled -> deep memory-level parallelism), accumulating:
//   s0 = sum x, sj = sum j*x, sk = sum k*x, sq = sum (j^2+k^2)*x
// plus per-lane argmax (value + flat index). Wave shuffle reduce, lane 0
// computes the closed-form per-sample loss:
//   loss = (mx^2+my^2)*s0 - 2*mx*sj - 2*my*sk + sq
// No LDS, no __syncthreads.
__global__ __launch_bounds__(256) void per_sample_loss(const float* __restrict__ x,
                                                       float* __restrict__ ws) {
    const int t    = threadIdx.x;
    const int lane = t & 63;
    const int wave = t >> 6;
    const int b    = blockIdx.x * 4 + wave;

    const float4* xp = (const float4*)(x + (size_t)b * HW);

    // Per-lane, per-component constants. Element index: e = 256*it + 4*lane + c.
    // k = e & 63 is constant per (lane,c); j = e>>6 = 4*it + j0_c.
    float kf[4], kk[4], jf[4];
    int   curIdx[4];
#pragma unroll
    for (int c = 0; c < 4; ++c) {
        const int e0 = 4 * lane + c;       // 0..255
        kf[c] = (float)(e0 & 63);
        kk[c] = kf[c] * kf[c];
        jf[c] = (float)(e0 >> 6);          // 0..3
        curIdx[c] = e0;
    }

    float s0 = 0.f, sj = 0.f, sk = 0.f, sq = 0.f;
    float maxv = -__builtin_inff();
    int   maxi = 0;

#pragma unroll
    for (int it = 0; it < 16; ++it) {
        const float4 v4 = xp[it * 64 + lane];
        const float vv[4] = {v4.x, v4.y, v4.z, v4.w};
#pragma unroll
        for (int c = 0; c < 4; ++c) {
            const float v = vv[c];
            const float q = fmaf(jf[c], jf[c], kk[c]);   // j^2 + k^2
            s0 += v;
            sj = fmaf(jf[c], v, sj);
            sk = fmaf(kf[c], v, sk);
            sq = fmaf(q, v, sq);
            // strict '>' + increasing scan order per lane => first max per lane
            const bool gt = v > maxv;
            maxv = gt ? v : maxv;
            maxi = gt ? curIdx[c] : maxi;
        }
#pragma unroll
        for (int c = 0; c < 4; ++c) { jf[c] += 4.0f; curIdx[c] += 256; }
    }

    // Wave-level reduction (64 lanes); ties -> smaller flat index (first max).
#pragma unroll
    for (int off = 32; off > 0; off >>= 1) {
        s0 += __shfl_down(s0, off);
        sj += __shfl_down(sj, off);
        sk += __shfl_down(sk, off);
        sq += __shfl_down(sq, off);
        const float ov = __shfl_down(maxv, off);
        const int   oi = __shfl_down(maxi, off);
        const bool take = (ov > maxv) || (ov == maxv && oi < maxi);
        maxv = take ? ov : maxv;
        maxi = take ? oi : maxi;
    }

    if (lane == 0) {
        const float mx = (float)(maxi >> 6);
        const float my = (float)(maxi & 63);
        ws[b] = (mx * mx + my * my) * s0 - 2.f * mx * sj - 2.f * my * sk + sq;
    }
}

__global__ __launch_bounds__(256) void final_reduce(const float* __restrict__ ws,
                                                    float* __restrict__ out) {
    const int t = threadIdx.x;
    float s = 0.f;
#pragma unroll
    for (int i = 0; i < NB / 256; ++i) s += ws[i * 256 + t];
#pragma unroll
    for (int off = 32; off > 0; off >>= 1) s += __shfl_down(s, off);
    __shared__ float l[4];
    if ((t & 63) == 0) l[t >> 6] = s;
    __syncthreads();
    if (t == 0) out[0] = l[0] + l[1] + l[2] + l[3];
}

extern "C" void kernel_launch(void* const* d_in, const int* in_sizes, int n_in,
                              void* d_out, int out_size, void* d_ws, size_t ws_size,
                              hipStream_t stream) {
    const float* x = (const float*)d_in[0];
    float* out = (float*)d_out;
    float* ws  = (float*)d_ws;   // 8192 floats = 32 KiB scratch

    per_sample_loss<<<NB / 4, 256, 0, stream>>>(x, ws);
    final_reduce<<<1, 256, 0, stream>>>(ws, out);
}